// Round 5
// baseline (1413.977 us; speedup 1.0000x reference)
//
#include <hip/hip_runtime.h>

#define N_NODES 65536
#define N_EDGES 1048576
#define N_LABEL 2097152
#define DIM_IN 32
#define DIM_H 64
#define NS16 (N_NODES * 16)   // floats per 16-dim slice

// ---------------- CSR build + norm precompute (round-3 version) ----------------

__global__ void k_init(float* __restrict__ deg, int* __restrict__ cnt) {
    int v = blockIdx.x * blockDim.x + threadIdx.x;
    deg[v] = 1.0f;  // self-loop weight
    cnt[v] = 0;
}

__global__ void k_cnt(const int* __restrict__ ei, const float* __restrict__ w,
                      int* __restrict__ cnt, float* __restrict__ deg) {
    int e = blockIdx.x * blockDim.x + threadIdx.x;
    int d = ei[N_EDGES + e];
    atomicAdd(&cnt[d], 1);
    atomicAdd(&deg[d], w[e]);
}

__global__ void k_scan(const int* __restrict__ cnt, int* __restrict__ offs,
                       int* __restrict__ cursor) {
    __shared__ int sums[257];
    int tid = threadIdx.x;
    int base = tid * 256;
    int s = 0;
    for (int i = 0; i < 256; ++i) s += cnt[base + i];
    sums[tid] = s;
    __syncthreads();
    if (tid == 0) {
        int run = 0;
        for (int i = 0; i < 256; ++i) { int t = sums[i]; sums[i] = run; run += t; }
    }
    __syncthreads();
    int run = sums[tid];
    for (int i = 0; i < 256; ++i) {
        offs[base + i] = run;
        cursor[base + i] = run;
        run += cnt[base + i];
    }
    if (tid == 255) offs[N_NODES] = run;
}

__global__ void k_dinv(float* __restrict__ deg) {
    int v = blockIdx.x * blockDim.x + threadIdx.x;
    deg[v] = rsqrtf(deg[v]);
}

__global__ void k_fill(const int* __restrict__ ei, const float* __restrict__ w,
                       const float* __restrict__ dinv, int* __restrict__ cursor,
                       int* __restrict__ csr_src, float* __restrict__ csr_nrm) {
    int e = blockIdx.x * blockDim.x + threadIdx.x;
    int s = ei[e];
    int d = ei[N_EDGES + e];
    int pos = atomicAdd(&cursor[d], 1);
    csr_src[pos] = s;
    csr_nrm[pos] = dinv[s] * w[e] * dinv[d];
}

// ---------------- slice x: xs[p][v][k] = x[v][p*16+k] (p<2) ----------------

__global__ void k_slice_x(const float* __restrict__ x, float* __restrict__ xs) {
    int gid = blockIdx.x * 256 + threadIdx.x;  // N*32 threads
    int v = gid >> 5, k = gid & 31;
    xs[(k >> 4) * NS16 + v * 16 + (k & 15)] = x[gid];
}

// ---------------- sliced aggregation ----------------
// grid = NSLICE*16384 blocks; slice = blockIdx.x>>14 (soft temporal ordering -> slice
// table (4 MB) is L2-resident while its blocks run). One 64-lane wave per node:
// 4 edge slots (e4 = lane>>4) x 16 dims (k = lane&15). Full degree loop per pass;
// output dims disjoint across slices -> no partial-sum RMW.

__global__ void __launch_bounds__(256) k_aggslice(
        const int* __restrict__ offs, const int* __restrict__ csr_src,
        const float* __restrict__ csr_nrm, const float* __restrict__ hs,
        const float* __restrict__ dinv, float* __restrict__ aggs) {
    int p  = blockIdx.x >> 14;
    int nb = blockIdx.x & 16383;
    const float* __restrict__ h_p = hs + (size_t)p * NS16;
    int tid = threadIdx.x;
    int v = nb * 4 + (tid >> 6);
    int lane = tid & 63;
    int e4 = lane >> 4;
    int k = lane & 15;

    float acc = 0.f;
    if (e4 == 0) {
        float dv = dinv[v];
        acc = dv * dv * h_p[v * 16 + k];  // self-loop term
    }
    int j0 = __builtin_amdgcn_readfirstlane(offs[v]);
    int j1 = __builtin_amdgcn_readfirstlane(offs[v + 1]);
    for (int j = j0 + e4; j < j1; j += 4) {
        int s = csr_src[j];          // broadcast within 16-lane subgroup
        float nm = csr_nrm[j];
        acc += nm * h_p[s * 16 + k]; // 64 B request per subgroup
    }
    acc += __shfl_xor(acc, 16);
    acc += __shfl_xor(acc, 32);
    if (lane < 16) aggs[(size_t)p * NS16 + v * 16 + k] = acc;
}

// ---------------- transform: outs = relu(agg @ W + b), sliced in & out ----------------

template <int K, bool RELU>
__global__ void __launch_bounds__(256) k_gemmb(
        const float* __restrict__ aggs, const float* __restrict__ W,
        const float* __restrict__ b, float* __restrict__ outs) {
    __shared__ float Wl[K * 64];
    int tid = threadIdx.x;
    for (int i = tid; i < K * 64; i += 256) Wl[i] = W[i];
    __syncthreads();
    int v = blockIdx.x * 4 + (tid >> 6);
    int lane = tid & 63;
    float kv = 0.f;
    if (lane < K) kv = aggs[(lane >> 4) * NS16 + v * 16 + (lane & 15)];
    float o0 = 0.f, o1 = 0.f, o2 = 0.f, o3 = 0.f;
#pragma unroll
    for (int kk = 0; kk < K; kk += 4) {
        o0 += __shfl(kv, kk + 0) * Wl[(kk + 0) * 64 + lane];
        o1 += __shfl(kv, kk + 1) * Wl[(kk + 1) * 64 + lane];
        o2 += __shfl(kv, kk + 2) * Wl[(kk + 2) * 64 + lane];
        o3 += __shfl(kv, kk + 3) * Wl[(kk + 3) * 64 + lane];
    }
    float o = (o0 + o1) + (o2 + o3) + b[lane];
    if (RELU) o = fmaxf(o, 0.f);
    outs[(lane >> 4) * NS16 + v * 16 + (lane & 15)] = o;
}

// ---------------- decode: 4 slice passes, out[p] (+)= dot16(enc_s[a], enc_s[b]) ----------------

template <bool FIRST>
__global__ void __launch_bounds__(256) k_decode_pass(
        const int* __restrict__ eli, const float* __restrict__ enc_p,
        float* __restrict__ out) {
    int gid = blockIdx.x * 256 + threadIdx.x;  // EL*4 threads
    int pr = gid >> 2;
    int q = gid & 3;
    int a = eli[pr];
    int b = eli[N_LABEL + pr];
    const float4 ea = *(const float4*)(enc_p + a * 16 + q * 4);
    const float4 eb = *(const float4*)(enc_p + b * 16 + q * 4);
    float s = ea.x * eb.x + ea.y * eb.y + ea.z * eb.z + ea.w * eb.w;
    s += __shfl_xor(s, 1, 4);
    s += __shfl_xor(s, 2, 4);
    if (q == 0) out[pr] = FIRST ? s : (out[pr] + s);
}

// ---------------- host ----------------

extern "C" void kernel_launch(void* const* d_in, const int* in_sizes, int n_in,
                              void* d_out, int out_size, void* d_ws, size_t ws_size,
                              hipStream_t stream) {
    const float* x   = (const float*)d_in[0];
    const int*   ei  = (const int*)d_in[1];
    const float* ew  = (const float*)d_in[2];
    const int*   eli = (const int*)d_in[3];
    const float* W[6] = {(const float*)d_in[4],  (const float*)d_in[6],
                         (const float*)d_in[8],  (const float*)d_in[10],
                         (const float*)d_in[12], (const float*)d_in[14]};
    const float* B[6] = {(const float*)d_in[5],  (const float*)d_in[7],
                         (const float*)d_in[9],  (const float*)d_in[11],
                         (const float*)d_in[13], (const float*)d_in[15]};

    char* ws = (char*)d_ws;
    float* dinv    = (float*)ws;  ws += N_NODES * 4;
    int*   cnt     = (int*)ws;    ws += N_NODES * 4;
    int*   offs    = (int*)ws;    ws += (N_NODES + 16) * 4;
    int*   cursor  = (int*)ws;    ws += N_NODES * 4;
    int*   csr_src = (int*)ws;    ws += N_EDGES * 4;
    float* csr_nrm = (float*)ws;  ws += N_EDGES * 4;
    float* xs      = (float*)ws;  ws += (size_t)2 * NS16 * 4;  // sliced x (2 slices)
    float* aggs    = (float*)ws;  ws += (size_t)4 * NS16 * 4;  // sliced agg scratch
    float* hsA     = (float*)ws;  ws += (size_t)4 * NS16 * 4;  // sliced features ping
    float* hsB     = (float*)ws;                               // sliced features pong

    const int BS = 256;
    const int gGemm = N_NODES / 4;

    // CSR build + norm
    k_init <<<N_NODES / BS, BS, 0, stream>>>(dinv, cnt);
    k_cnt  <<<N_EDGES / BS, BS, 0, stream>>>(ei, ew, cnt, dinv);
    k_scan <<<1, 256, 0, stream>>>(cnt, offs, cursor);
    k_dinv <<<N_NODES / BS, BS, 0, stream>>>(dinv);
    k_fill <<<N_EDGES / BS, BS, 0, stream>>>(ei, ew, dinv, cursor, csr_src, csr_nrm);

    // slice x
    k_slice_x<<<N_NODES * 32 / BS, BS, 0, stream>>>(x, xs);

    // layer 1: xs (2 slices) -> aggs -> hsA
    k_aggslice<<<2 * 16384, BS, 0, stream>>>(offs, csr_src, csr_nrm, xs, dinv, aggs);
    k_gemmb<DIM_IN, true><<<gGemm, BS, 0, stream>>>(aggs, W[0], B[0], hsA);

    // layers 2..5: 4-slice agg + transform (ping-pong)
    float* cur = hsA;
    float* nxt = hsB;
    for (int l = 1; l < 5; ++l) {
        k_aggslice<<<4 * 16384, BS, 0, stream>>>(offs, csr_src, csr_nrm, cur, dinv, aggs);
        k_gemmb<DIM_H, true><<<gGemm, BS, 0, stream>>>(aggs, W[l], B[l], nxt);
        float* t = cur; cur = nxt; nxt = t;
    }

    // layer 6 (no relu) -> enc (sliced) in nxt
    k_aggslice<<<4 * 16384, BS, 0, stream>>>(offs, csr_src, csr_nrm, cur, dinv, aggs);
    k_gemmb<DIM_H, false><<<gGemm, BS, 0, stream>>>(aggs, W[5], B[5], nxt);
    const float* enc = nxt;

    // decode: 4 slice passes
    const int gDec = N_LABEL * 4 / BS;
    k_decode_pass<true ><<<gDec, BS, 0, stream>>>(eli, enc + 0 * NS16, (float*)d_out);
    k_decode_pass<false><<<gDec, BS, 0, stream>>>(eli, enc + 1 * NS16, (float*)d_out);
    k_decode_pass<false><<<gDec, BS, 0, stream>>>(eli, enc + 2 * NS16, (float*)d_out);
    k_decode_pass<false><<<gDec, BS, 0, stream>>>(eli, enc + 3 * NS16, (float*)d_out);
}

// Round 6
// 1163.305 us; speedup vs baseline: 1.2155x; 1.2155x over previous
//
#include <hip/hip_runtime.h>

#define N_NODES 65536
#define N_EDGES 1048576
#define N_LABEL 2097152
#define DIM_IN 32
#define DIM_H 64
#define NS16 (N_NODES * 16)   // floats per 16-dim slice

// ---------------- CSR build + norm precompute ----------------

__global__ void k_init(float* __restrict__ deg, int* __restrict__ cnt) {
    int v = blockIdx.x * blockDim.x + threadIdx.x;
    deg[v] = 1.0f;  // self-loop weight
    cnt[v] = 0;
}

__global__ void k_cnt(const int* __restrict__ ei, const float* __restrict__ w,
                      int* __restrict__ cnt, float* __restrict__ deg) {
    int e = blockIdx.x * blockDim.x + threadIdx.x;
    int d = ei[N_EDGES + e];
    atomicAdd(&cnt[d], 1);
    atomicAdd(&deg[d], w[e]);
}

// hierarchical exclusive scan over cnt[N] (64 blocks x 1024)
__global__ void k_scan1(const int* __restrict__ cnt, int* __restrict__ blksum) {
    int tid = threadIdx.x;
    const int4* p = (const int4*)(cnt + blockIdx.x * 1024);
    int4 v = p[tid];
    int s = v.x + v.y + v.z + v.w;
    for (int d = 1; d < 64; d <<= 1) s += __shfl_xor(s, d);
    __shared__ int wsum[4];
    if ((tid & 63) == 0) wsum[tid >> 6] = s;
    __syncthreads();
    if (tid == 0) blksum[blockIdx.x] = wsum[0] + wsum[1] + wsum[2] + wsum[3];
}

__global__ void k_scan2(int* __restrict__ blksum) {
    if (threadIdx.x == 0) {
        int run = 0;
        for (int i = 0; i < 64; ++i) { int t = blksum[i]; blksum[i] = run; run += t; }
    }
}

__global__ void k_scan3(const int* __restrict__ cnt, const int* __restrict__ blksum,
                        int* __restrict__ offs, int* __restrict__ cursor) {
    int tid = threadIdx.x, bid = blockIdx.x;
    const int4* p = (const int4*)(cnt + bid * 1024);
    int4 v = p[tid];
    int s = v.x + v.y + v.z + v.w;
    int lane = tid & 63, wid = tid >> 6;
    int sc = s;
    for (int d = 1; d < 64; d <<= 1) {
        int t = __shfl_up(sc, d);
        if (lane >= d) sc += t;
    }
    __shared__ int wsum[4];
    if (lane == 63) wsum[wid] = sc;
    __syncthreads();
    int base = blksum[bid];
    for (int w2 = 0; w2 < wid; ++w2) base += wsum[w2];
    int ex = base + sc - s;  // exclusive prefix of this thread's 4 entries
    int idx = bid * 1024 + tid * 4;
    int o0 = ex, o1 = o0 + v.x, o2 = o1 + v.y, o3 = o2 + v.z;
    offs[idx] = o0; offs[idx + 1] = o1; offs[idx + 2] = o2; offs[idx + 3] = o3;
    cursor[idx] = o0; cursor[idx + 1] = o1; cursor[idx + 2] = o2; cursor[idx + 3] = o3;
    if (bid == 63 && tid == 255) offs[N_NODES] = o3 + v.w;  // == N_EDGES
}

__global__ void k_dinv(float* __restrict__ deg) {
    int v = blockIdx.x * blockDim.x + threadIdx.x;
    deg[v] = rsqrtf(deg[v]);
}

__global__ void k_fill(const int* __restrict__ ei, const float* __restrict__ w,
                       const float* __restrict__ dinv, int* __restrict__ cursor,
                       int* __restrict__ csr_src, float* __restrict__ csr_nrm) {
    int e = blockIdx.x * blockDim.x + threadIdx.x;
    int s = ei[e];
    int d = ei[N_EDGES + e];
    int pos = atomicAdd(&cursor[d], 1);
    csr_src[pos] = s;
    csr_nrm[pos] = dinv[s] * w[e] * dinv[d];
}

// ---------------- slice x: xs[p][v][k] = x[v][p*16+k] (p<2) ----------------

__global__ void k_slice_x(const float* __restrict__ x, float* __restrict__ xs) {
    int gid = blockIdx.x * 256 + threadIdx.x;  // N*32 threads
    int v = gid >> 5, k = gid & 31;
    xs[(k >> 4) * NS16 + v * 16 + (k & 15)] = x[gid];
}

// ---------------- sliced aggregation, 4-deep MLP per subgroup ----------------
// slice = blockIdx.x>>14 (slice-major soft ordering -> 4 MB slice table L2-resident;
// round-5 measured FETCH = cold replication only). One 64-lane wave per node:
// subgroup e4 = lane>>4 handles edges j0+e4, +4, +8, +12 with 4 independent
// accumulators -> 16 outstanding 64 B gathers per wave (round 5 had 4).
// Tail edges: index clamped to a valid slot, norm zeroed (no divergence).

__global__ void __launch_bounds__(256) k_aggslice(
        const int* __restrict__ offs, const int* __restrict__ csr_src,
        const float* __restrict__ csr_nrm, const float* __restrict__ hs,
        const float* __restrict__ dinv, float* __restrict__ aggs) {
    int p  = blockIdx.x >> 14;
    int nb = blockIdx.x & 16383;
    const float* __restrict__ h_p = hs + (size_t)p * NS16;
    int tid = threadIdx.x;
    int v = nb * 4 + (tid >> 6);
    int lane = tid & 63;
    int e4 = lane >> 4;
    int k = lane & 15;

    int j0 = __builtin_amdgcn_readfirstlane(offs[v]);
    int j1 = __builtin_amdgcn_readfirstlane(offs[v + 1]);

    float a0 = 0.f, a1 = 0.f, a2 = 0.f, a3 = 0.f;
    if (e4 == 0) {
        float dv = dinv[v];
        a0 = dv * dv * h_p[v * 16 + k];  // self-loop term
    }
    for (int j = j0 + e4; j < j1; j += 16) {
        int jB = j + 4, jC = j + 8, jD = j + 12;
        int sA = csr_src[j];
        float nA = csr_nrm[j];
        int sB = csr_src[jB < j1 ? jB : j];
        float nB = jB < j1 ? csr_nrm[jB] : 0.f;
        int sC = csr_src[jC < j1 ? jC : j];
        float nC = jC < j1 ? csr_nrm[jC] : 0.f;
        int sD = csr_src[jD < j1 ? jD : j];
        float nD = jD < j1 ? csr_nrm[jD] : 0.f;
        a0 += nA * h_p[sA * 16 + k];
        a1 += nB * h_p[sB * 16 + k];
        a2 += nC * h_p[sC * 16 + k];
        a3 += nD * h_p[sD * 16 + k];
    }
    float acc = (a0 + a1) + (a2 + a3);
    acc += __shfl_xor(acc, 16);
    acc += __shfl_xor(acc, 32);
    if (lane < 16) aggs[(size_t)p * NS16 + v * 16 + k] = acc;
}

// ---------------- transform: out = relu(agg @ W + b) ----------------

template <int K, bool RELU, bool SLICED_OUT>
__global__ void __launch_bounds__(256) k_gemmb(
        const float* __restrict__ aggs, const float* __restrict__ W,
        const float* __restrict__ b, float* __restrict__ outs) {
    __shared__ float Wl[K * 64];
    int tid = threadIdx.x;
    for (int i = tid; i < K * 64; i += 256) Wl[i] = W[i];
    __syncthreads();
    int v = blockIdx.x * 4 + (tid >> 6);
    int lane = tid & 63;
    float kv = 0.f;
    if (lane < K) kv = aggs[(lane >> 4) * NS16 + v * 16 + (lane & 15)];
    float o0 = 0.f, o1 = 0.f, o2 = 0.f, o3 = 0.f;
#pragma unroll
    for (int kk = 0; kk < K; kk += 4) {
        o0 += __shfl(kv, kk + 0) * Wl[(kk + 0) * 64 + lane];
        o1 += __shfl(kv, kk + 1) * Wl[(kk + 1) * 64 + lane];
        o2 += __shfl(kv, kk + 2) * Wl[(kk + 2) * 64 + lane];
        o3 += __shfl(kv, kk + 3) * Wl[(kk + 3) * 64 + lane];
    }
    float o = (o0 + o1) + (o2 + o3) + b[lane];
    if (RELU) o = fmaxf(o, 0.f);
    if (SLICED_OUT) outs[(lane >> 4) * NS16 + v * 16 + (lane & 15)] = o;
    else            outs[(size_t)v * 64 + lane] = o;
}

// ---------------- decode: out[p] = dot(enc[a], enc[b]) (single pass, 256 B gathers) ----------------

__global__ void k_decode(const int* __restrict__ eli, const float4* __restrict__ enc4,
                         float* __restrict__ out) {
    int gid = blockIdx.x * blockDim.x + threadIdx.x;  // EL*16 threads
    int p = gid >> 4;
    int c4 = gid & 15;
    int a = eli[p];
    int b = eli[N_LABEL + p];
    float4 ea = enc4[(size_t)a * 16 + c4];
    float4 eb = enc4[(size_t)b * 16 + c4];
    float s = ea.x * eb.x + ea.y * eb.y + ea.z * eb.z + ea.w * eb.w;
#pragma unroll
    for (int m = 8; m >= 1; m >>= 1) s += __shfl_xor(s, m, 16);
    if (c4 == 0) out[p] = s;
}

// ---------------- host ----------------

extern "C" void kernel_launch(void* const* d_in, const int* in_sizes, int n_in,
                              void* d_out, int out_size, void* d_ws, size_t ws_size,
                              hipStream_t stream) {
    const float* x   = (const float*)d_in[0];
    const int*   ei  = (const int*)d_in[1];
    const float* ew  = (const float*)d_in[2];
    const int*   eli = (const int*)d_in[3];
    const float* W[6] = {(const float*)d_in[4],  (const float*)d_in[6],
                         (const float*)d_in[8],  (const float*)d_in[10],
                         (const float*)d_in[12], (const float*)d_in[14]};
    const float* B[6] = {(const float*)d_in[5],  (const float*)d_in[7],
                         (const float*)d_in[9],  (const float*)d_in[11],
                         (const float*)d_in[13], (const float*)d_in[15]};

    char* ws = (char*)d_ws;
    float* dinv    = (float*)ws;  ws += N_NODES * 4;
    int*   cnt     = (int*)ws;    ws += N_NODES * 4;
    int*   offs    = (int*)ws;    ws += (N_NODES + 16) * 4;
    int*   cursor  = (int*)ws;    ws += N_NODES * 4;
    int*   blksum  = (int*)ws;    ws += 256 * 4;
    int*   csr_src = (int*)ws;    ws += N_EDGES * 4;
    float* csr_nrm = (float*)ws;  ws += N_EDGES * 4;
    float* xs      = (float*)ws;  ws += (size_t)2 * NS16 * 4;  // sliced x
    float* aggs    = (float*)ws;  ws += (size_t)4 * NS16 * 4;  // sliced agg scratch
    float* hsA     = (float*)ws;  ws += (size_t)4 * NS16 * 4;  // sliced features ping
    float* hsB     = (float*)ws;                               // sliced pong / final enc (unsliced)

    const int BS = 256;
    const int gGemm = N_NODES / 4;

    // CSR build + norm
    k_init <<<N_NODES / BS, BS, 0, stream>>>(dinv, cnt);
    k_cnt  <<<N_EDGES / BS, BS, 0, stream>>>(ei, ew, cnt, dinv);
    k_scan1<<<64, BS, 0, stream>>>(cnt, blksum);
    k_scan2<<<1, 64, 0, stream>>>(blksum);
    k_scan3<<<64, BS, 0, stream>>>(cnt, blksum, offs, cursor);
    k_dinv <<<N_NODES / BS, BS, 0, stream>>>(dinv);
    k_fill <<<N_EDGES / BS, BS, 0, stream>>>(ei, ew, dinv, cursor, csr_src, csr_nrm);

    // slice x
    k_slice_x<<<N_NODES * 32 / BS, BS, 0, stream>>>(x, xs);

    // layer 1: xs (2 slices) -> aggs -> hsA (sliced)
    k_aggslice<<<2 * 16384, BS, 0, stream>>>(offs, csr_src, csr_nrm, xs, dinv, aggs);
    k_gemmb<DIM_IN, true, true><<<gGemm, BS, 0, stream>>>(aggs, W[0], B[0], hsA);

    // layers 2..5 (sliced ping-pong)
    float* cur = hsA;
    float* nxt = hsB;
    for (int l = 1; l < 5; ++l) {
        k_aggslice<<<4 * 16384, BS, 0, stream>>>(offs, csr_src, csr_nrm, cur, dinv, aggs);
        k_gemmb<DIM_H, true, true><<<gGemm, BS, 0, stream>>>(aggs, W[l], B[l], nxt);
        float* t = cur; cur = nxt; nxt = t;
    }

    // layer 6: transform writes UNSLICED enc (feeds decode directly)
    k_aggslice<<<4 * 16384, BS, 0, stream>>>(offs, csr_src, csr_nrm, cur, dinv, aggs);
    k_gemmb<DIM_H, false, false><<<gGemm, BS, 0, stream>>>(aggs, W[5], B[5], nxt);
    const float* enc = nxt;

    // decode (single pass)
    k_decode<<<N_LABEL * 16 / BS, BS, 0, stream>>>(eli, (const float4*)enc, (float*)d_out);
}

// Round 7
// 756.265 us; speedup vs baseline: 1.8697x; 1.5382x over previous
//
#include <hip/hip_runtime.h>
#include <hip/hip_fp16.h>

#define N_NODES 65536
#define N_EDGES 1048576
#define N_LABEL 2097152
#define DIM_IN 32
#define DIM_H 64

// ---------------- CSR build + norm precompute ----------------

__global__ void k_init(float* __restrict__ deg, int* __restrict__ cnt) {
    int v = blockIdx.x * blockDim.x + threadIdx.x;
    deg[v] = 1.0f;  // self-loop weight
    cnt[v] = 0;
}

__global__ void k_cnt(const int* __restrict__ ei, const float* __restrict__ w,
                      int* __restrict__ cnt, float* __restrict__ deg) {
    int e = blockIdx.x * blockDim.x + threadIdx.x;
    int d = ei[N_EDGES + e];
    atomicAdd(&cnt[d], 1);
    atomicAdd(&deg[d], w[e]);
}

// hierarchical exclusive scan over cnt[N] (64 blocks x 1024)
__global__ void k_scan1(const int* __restrict__ cnt, int* __restrict__ blksum) {
    int tid = threadIdx.x;
    const int4* p = (const int4*)(cnt + blockIdx.x * 1024);
    int4 v = p[tid];
    int s = v.x + v.y + v.z + v.w;
    for (int d = 1; d < 64; d <<= 1) s += __shfl_xor(s, d);
    __shared__ int wsum[4];
    if ((tid & 63) == 0) wsum[tid >> 6] = s;
    __syncthreads();
    if (tid == 0) blksum[blockIdx.x] = wsum[0] + wsum[1] + wsum[2] + wsum[3];
}

__global__ void k_scan2(int* __restrict__ blksum) {
    if (threadIdx.x == 0) {
        int run = 0;
        for (int i = 0; i < 64; ++i) { int t = blksum[i]; blksum[i] = run; run += t; }
    }
}

__global__ void k_scan3(const int* __restrict__ cnt, const int* __restrict__ blksum,
                        int* __restrict__ offs, int* __restrict__ cursor) {
    int tid = threadIdx.x, bid = blockIdx.x;
    const int4* p = (const int4*)(cnt + bid * 1024);
    int4 v = p[tid];
    int s = v.x + v.y + v.z + v.w;
    int lane = tid & 63, wid = tid >> 6;
    int sc = s;
    for (int d = 1; d < 64; d <<= 1) {
        int t = __shfl_up(sc, d);
        if (lane >= d) sc += t;
    }
    __shared__ int wsum[4];
    if (lane == 63) wsum[wid] = sc;
    __syncthreads();
    int base = blksum[bid];
    for (int w2 = 0; w2 < wid; ++w2) base += wsum[w2];
    int ex = base + sc - s;  // exclusive prefix of this thread's 4 entries
    int idx = bid * 1024 + tid * 4;
    int o0 = ex, o1 = o0 + v.x, o2 = o1 + v.y, o3 = o2 + v.z;
    offs[idx] = o0; offs[idx + 1] = o1; offs[idx + 2] = o2; offs[idx + 3] = o3;
    cursor[idx] = o0; cursor[idx + 1] = o1; cursor[idx + 2] = o2; cursor[idx + 3] = o3;
    if (bid == 63 && tid == 255) offs[N_NODES] = o3 + v.w;  // == N_EDGES
}

__global__ void k_dinv(float* __restrict__ deg) {
    int v = blockIdx.x * blockDim.x + threadIdx.x;
    deg[v] = rsqrtf(deg[v]);
}

__global__ void k_fill(const int* __restrict__ ei, const float* __restrict__ w,
                       const float* __restrict__ dinv, int* __restrict__ cursor,
                       int* __restrict__ csr_src, float* __restrict__ csr_nrm) {
    int e = blockIdx.x * blockDim.x + threadIdx.x;
    int s = ei[e];
    int d = ei[N_EDGES + e];
    int pos = atomicAdd(&cursor[d], 1);
    csr_src[pos] = s;
    csr_nrm[pos] = dinv[s] * w[e] * dinv[d];
}

// ---------------- cast x to fp16 ----------------

__global__ void k_cast_x(const float* __restrict__ x, __half* __restrict__ xh) {
    int gid = blockIdx.x * 256 + threadIdx.x;  // N*32 threads
    xh[gid] = __float2half(x[gid]);
}

// ---------------- fused layer: out[v] = half( relu( (Ah)[v] @ W + b ) ) ----------------
// One 64-lane wave per node; fp16 feature table (128 B row gathers), fp32 math.

template <int K, bool RELU>
__global__ void __launch_bounds__(256) k_layer(
        const int* __restrict__ offs, const int* __restrict__ csr_src,
        const float* __restrict__ csr_nrm, const __half* __restrict__ h,
        const float* __restrict__ dinv, const float* __restrict__ W,
        const float* __restrict__ b, __half* __restrict__ out) {
    __shared__ float Wl[K * 64];
    int tid = threadIdx.x;
    for (int i = tid; i < K * 64; i += 256) Wl[i] = W[i];
    __syncthreads();

    int v = blockIdx.x * 4 + (tid >> 6);
    int lane = tid & 63;
    int k = lane & (K - 1);

    float dv = dinv[v];
    float acc = dv * dv * __half2float(h[(size_t)v * K + k]);  // self-loop term

    int j0 = __builtin_amdgcn_readfirstlane(offs[v]);
    int j1 = __builtin_amdgcn_readfirstlane(offs[v + 1]);
    int j = j0;
    for (; j + 8 <= j1; j += 8) {
        int s0 = __builtin_amdgcn_readfirstlane(csr_src[j + 0]);
        int s1 = __builtin_amdgcn_readfirstlane(csr_src[j + 1]);
        int s2 = __builtin_amdgcn_readfirstlane(csr_src[j + 2]);
        int s3 = __builtin_amdgcn_readfirstlane(csr_src[j + 3]);
        int s4 = __builtin_amdgcn_readfirstlane(csr_src[j + 4]);
        int s5 = __builtin_amdgcn_readfirstlane(csr_src[j + 5]);
        int s6 = __builtin_amdgcn_readfirstlane(csr_src[j + 6]);
        int s7 = __builtin_amdgcn_readfirstlane(csr_src[j + 7]);
        float n0 = csr_nrm[j + 0], n1 = csr_nrm[j + 1];
        float n2 = csr_nrm[j + 2], n3 = csr_nrm[j + 3];
        float n4 = csr_nrm[j + 4], n5 = csr_nrm[j + 5];
        float n6 = csr_nrm[j + 6], n7 = csr_nrm[j + 7];
        float r0 = __half2float(h[(size_t)s0 * K + k]);
        float r1 = __half2float(h[(size_t)s1 * K + k]);
        float r2 = __half2float(h[(size_t)s2 * K + k]);
        float r3 = __half2float(h[(size_t)s3 * K + k]);
        float r4 = __half2float(h[(size_t)s4 * K + k]);
        float r5 = __half2float(h[(size_t)s5 * K + k]);
        float r6 = __half2float(h[(size_t)s6 * K + k]);
        float r7 = __half2float(h[(size_t)s7 * K + k]);
        acc += n0 * r0; acc += n1 * r1; acc += n2 * r2; acc += n3 * r3;
        acc += n4 * r4; acc += n5 * r5; acc += n6 * r6; acc += n7 * r7;
    }
    for (; j < j1; ++j) {
        int s = __builtin_amdgcn_readfirstlane(csr_src[j]);
        acc += csr_nrm[j] * __half2float(h[(size_t)s * K + k]);
    }

    // transform: o[lane] = sum_k acc[k] * W[k][lane]
    float o0 = 0.f, o1 = 0.f, o2 = 0.f, o3 = 0.f;
#pragma unroll
    for (int kk = 0; kk < K; kk += 4) {
        o0 += __shfl(acc, kk + 0) * Wl[(kk + 0) * 64 + lane];
        o1 += __shfl(acc, kk + 1) * Wl[(kk + 1) * 64 + lane];
        o2 += __shfl(acc, kk + 2) * Wl[(kk + 2) * 64 + lane];
        o3 += __shfl(acc, kk + 3) * Wl[(kk + 3) * 64 + lane];
    }
    float o = (o0 + o1) + (o2 + o3) + b[lane];
    if (RELU) o = fmaxf(o, 0.f);
    out[(size_t)v * 64 + lane] = __float2half(o);
}

// ---------------- decode: out[p] = dot(enc[a], enc[b]); 8 lanes/pair, fp16 rows ----------------

__device__ __forceinline__ float dot8h(uint4 ua, uint4 ub) {
    const __half2* pa = (const __half2*)&ua;
    const __half2* pb = (const __half2*)&ub;
    float s = 0.f;
#pragma unroll
    for (int i = 0; i < 4; ++i) {
        float2 fa = __half22float2(pa[i]);
        float2 fb = __half22float2(pb[i]);
        s += fa.x * fb.x + fa.y * fb.y;
    }
    return s;
}

__global__ void __launch_bounds__(256) k_decode(
        const int* __restrict__ eli, const __half* __restrict__ enc,
        float* __restrict__ out) {
    int gid = blockIdx.x * 256 + threadIdx.x;  // EL*8 threads
    int p = gid >> 3;
    int c8 = gid & 7;  // 8 halves (16 B) per lane
    int a = eli[p];
    int b = eli[N_LABEL + p];
    uint4 ua = *(const uint4*)(enc + (size_t)a * 64 + c8 * 8);
    uint4 ub = *(const uint4*)(enc + (size_t)b * 64 + c8 * 8);
    float s = dot8h(ua, ub);
    s += __shfl_xor(s, 1, 8);
    s += __shfl_xor(s, 2, 8);
    s += __shfl_xor(s, 4, 8);
    if (c8 == 0) out[p] = s;
}

// ---------------- host ----------------

extern "C" void kernel_launch(void* const* d_in, const int* in_sizes, int n_in,
                              void* d_out, int out_size, void* d_ws, size_t ws_size,
                              hipStream_t stream) {
    const float* x   = (const float*)d_in[0];
    const int*   ei  = (const int*)d_in[1];
    const float* ew  = (const float*)d_in[2];
    const int*   eli = (const int*)d_in[3];
    const float* W[6] = {(const float*)d_in[4],  (const float*)d_in[6],
                         (const float*)d_in[8],  (const float*)d_in[10],
                         (const float*)d_in[12], (const float*)d_in[14]};
    const float* B[6] = {(const float*)d_in[5],  (const float*)d_in[7],
                         (const float*)d_in[9],  (const float*)d_in[11],
                         (const float*)d_in[13], (const float*)d_in[15]};

    char* ws = (char*)d_ws;
    float*  dinv    = (float*)ws;   ws += N_NODES * 4;
    int*    cnt     = (int*)ws;     ws += N_NODES * 4;
    int*    offs    = (int*)ws;     ws += (N_NODES + 16) * 4;
    int*    cursor  = (int*)ws;     ws += N_NODES * 4;
    int*    blksum  = (int*)ws;     ws += 256 * 4;
    int*    csr_src = (int*)ws;     ws += N_EDGES * 4;
    float*  csr_nrm = (float*)ws;   ws += N_EDGES * 4;
    __half* xh      = (__half*)ws;  ws += (size_t)N_NODES * DIM_IN * 2;
    __half* hA      = (__half*)ws;  ws += (size_t)N_NODES * 64 * 2;
    __half* hB      = (__half*)ws;

    const int BS = 256;
    const int gLayer = N_NODES / 4;  // one 64-lane wave per node, 4 per block

    // CSR build + norm
    k_init <<<N_NODES / BS, BS, 0, stream>>>(dinv, cnt);
    k_cnt  <<<N_EDGES / BS, BS, 0, stream>>>(ei, ew, cnt, dinv);
    k_scan1<<<64, BS, 0, stream>>>(cnt, blksum);
    k_scan2<<<1, 64, 0, stream>>>(blksum);
    k_scan3<<<64, BS, 0, stream>>>(cnt, blksum, offs, cursor);
    k_dinv <<<N_NODES / BS, BS, 0, stream>>>(dinv);
    k_fill <<<N_EDGES / BS, BS, 0, stream>>>(ei, ew, dinv, cursor, csr_src, csr_nrm);

    // cast x to fp16
    k_cast_x<<<N_NODES * DIM_IN / BS, BS, 0, stream>>>(x, xh);

    // fused layers (fp16 tables, fp32 math)
    k_layer<DIM_IN, true ><<<gLayer, BS, 0, stream>>>(offs, csr_src, csr_nrm, xh, dinv, W[0], B[0], hA);
    k_layer<DIM_H,  true ><<<gLayer, BS, 0, stream>>>(offs, csr_src, csr_nrm, hA, dinv, W[1], B[1], hB);
    k_layer<DIM_H,  true ><<<gLayer, BS, 0, stream>>>(offs, csr_src, csr_nrm, hB, dinv, W[2], B[2], hA);
    k_layer<DIM_H,  true ><<<gLayer, BS, 0, stream>>>(offs, csr_src, csr_nrm, hA, dinv, W[3], B[3], hB);
    k_layer<DIM_H,  true ><<<gLayer, BS, 0, stream>>>(offs, csr_src, csr_nrm, hB, dinv, W[4], B[4], hA);
    k_layer<DIM_H, false><<<gLayer, BS, 0, stream>>>(offs, csr_src, csr_nrm, hA, dinv, W[5], B[5], hB);

    // decode (8 lanes per pair)
    k_decode<<<N_LABEL * 8 / BS, BS, 0, stream>>>(eli, hB, (float*)d_out);
}

// Round 8
// 738.997 us; speedup vs baseline: 1.9134x; 1.0234x over previous
//
#include <hip/hip_runtime.h>
#include <hip/hip_fp16.h>

#define N_NODES 65536
#define N_EDGES 1048576
#define N_LABEL 2097152
#define DIM_IN 32
#define DIM_H 64

// ---------------- CSR build + norm precompute ----------------

__global__ void k_init(float* __restrict__ deg, int* __restrict__ cnt) {
    int v = blockIdx.x * blockDim.x + threadIdx.x;
    deg[v] = 1.0f;  // self-loop weight
    cnt[v] = 0;
}

__global__ void k_cnt(const int* __restrict__ ei, const float* __restrict__ w,
                      int* __restrict__ cnt, float* __restrict__ deg) {
    int e = blockIdx.x * blockDim.x + threadIdx.x;
    int d = ei[N_EDGES + e];
    atomicAdd(&cnt[d], 1);
    atomicAdd(&deg[d], w[e]);
}

// hierarchical exclusive scan over cnt[N] (64 blocks x 1024)
__global__ void k_scan1(const int* __restrict__ cnt, int* __restrict__ blksum) {
    int tid = threadIdx.x;
    const int4* p = (const int4*)(cnt + blockIdx.x * 1024);
    int4 v = p[tid];
    int s = v.x + v.y + v.z + v.w;
    for (int d = 1; d < 64; d <<= 1) s += __shfl_xor(s, d);
    __shared__ int wsum[4];
    if ((tid & 63) == 0) wsum[tid >> 6] = s;
    __syncthreads();
    if (tid == 0) blksum[blockIdx.x] = wsum[0] + wsum[1] + wsum[2] + wsum[3];
}

__global__ void k_scan2(int* __restrict__ blksum) {
    if (threadIdx.x == 0) {
        int run = 0;
        for (int i = 0; i < 64; ++i) { int t = blksum[i]; blksum[i] = run; run += t; }
    }
}

__global__ void k_scan3(const int* __restrict__ cnt, const int* __restrict__ blksum,
                        int* __restrict__ offs, int* __restrict__ cursor) {
    int tid = threadIdx.x, bid = blockIdx.x;
    const int4* p = (const int4*)(cnt + bid * 1024);
    int4 v = p[tid];
    int s = v.x + v.y + v.z + v.w;
    int lane = tid & 63, wid = tid >> 6;
    int sc = s;
    for (int d = 1; d < 64; d <<= 1) {
        int t = __shfl_up(sc, d);
        if (lane >= d) sc += t;
    }
    __shared__ int wsum[4];
    if (lane == 63) wsum[wid] = sc;
    __syncthreads();
    int base = blksum[bid];
    for (int w2 = 0; w2 < wid; ++w2) base += wsum[w2];
    int ex = base + sc - s;  // exclusive prefix of this thread's 4 entries
    int idx = bid * 1024 + tid * 4;
    int o0 = ex, o1 = o0 + v.x, o2 = o1 + v.y, o3 = o2 + v.z;
    offs[idx] = o0; offs[idx + 1] = o1; offs[idx + 2] = o2; offs[idx + 3] = o3;
    cursor[idx] = o0; cursor[idx + 1] = o1; cursor[idx + 2] = o2; cursor[idx + 3] = o3;
    if (bid == 63 && tid == 255) offs[N_NODES] = o3 + v.w;  // == N_EDGES
}

__global__ void k_dinv(float* __restrict__ deg) {
    int v = blockIdx.x * blockDim.x + threadIdx.x;
    deg[v] = rsqrtf(deg[v]);
}

// packed CSR entry: {src, norm-as-bits}
__global__ void k_fill(const int* __restrict__ ei, const float* __restrict__ w,
                       const float* __restrict__ dinv, int* __restrict__ cursor,
                       int2* __restrict__ csr_se) {
    int e = blockIdx.x * blockDim.x + threadIdx.x;
    int s = ei[e];
    int d = ei[N_EDGES + e];
    int pos = atomicAdd(&cursor[d], 1);
    float nm = dinv[s] * w[e] * dinv[d];
    csr_se[pos] = make_int2(s, __float_as_int(nm));
}

// ---------------- cast x to fp16 ----------------

__global__ void k_cast_x(const float* __restrict__ x, __half* __restrict__ xh) {
    int gid = blockIdx.x * 256 + threadIdx.x;  // N*32 threads
    xh[gid] = __float2half(x[gid]);
}

// ---------------- fused layer: out[v] = half( relu( (Ah)[v] @ W + b ) ) ----------------
// One 64-lane wave per node; fp16 feature table (128 B row gathers), fp32 math.
// Edge loop: 16-deep independent gather blocks; tail edges predicated by
// clamping the index to j0 and zeroing the norm (no divergence, no tail loop).

template <int K, bool RELU>
__global__ void __launch_bounds__(256) k_layer(
        const int* __restrict__ offs, const int2* __restrict__ csr_se,
        const __half* __restrict__ h, const float* __restrict__ dinv,
        const float* __restrict__ W, const float* __restrict__ b,
        __half* __restrict__ out) {
    __shared__ float Wl[K * 64];
    int tid = threadIdx.x;
    for (int i = tid; i < K * 64; i += 256) Wl[i] = W[i];
    __syncthreads();

    int v = blockIdx.x * 4 + (tid >> 6);
    int lane = tid & 63;
    int k = lane & (K - 1);

    float dv = dinv[v];
    float acc = dv * dv * __half2float(h[(size_t)v * K + k]);  // self-loop term

    int j0 = __builtin_amdgcn_readfirstlane(offs[v]);
    int j1 = __builtin_amdgcn_readfirstlane(offs[v + 1]);

    for (int j = j0; j < j1; j += 16) {
        float rr[16], nn[16];
#pragma unroll
        for (int u = 0; u < 16; ++u) {
            int jj = j + u;
            int2 se = csr_se[jj < j1 ? jj : j0];
            int s = __builtin_amdgcn_readfirstlane(se.x);
            int nbits = __builtin_amdgcn_readfirstlane(se.y);
            nn[u] = (jj < j1) ? __int_as_float(nbits) : 0.f;
            rr[u] = __half2float(h[(size_t)s * K + k]);
        }
#pragma unroll
        for (int u = 0; u < 16; ++u) acc += nn[u] * rr[u];
    }

    // transform: o[lane] = sum_k acc[k] * W[k][lane]
    float o0 = 0.f, o1 = 0.f, o2 = 0.f, o3 = 0.f;
#pragma unroll
    for (int kk = 0; kk < K; kk += 4) {
        o0 += __shfl(acc, kk + 0) * Wl[(kk + 0) * 64 + lane];
        o1 += __shfl(acc, kk + 1) * Wl[(kk + 1) * 64 + lane];
        o2 += __shfl(acc, kk + 2) * Wl[(kk + 2) * 64 + lane];
        o3 += __shfl(acc, kk + 3) * Wl[(kk + 3) * 64 + lane];
    }
    float o = (o0 + o1) + (o2 + o3) + b[lane];
    if (RELU) o = fmaxf(o, 0.f);
    out[(size_t)v * 64 + lane] = __float2half(o);
}

// ---------------- decode: out[p] = dot(enc[a], enc[b]); 8 lanes/pair, fp16 rows ----------------

__device__ __forceinline__ float dot8h(uint4 ua, uint4 ub) {
    const __half2* pa = (const __half2*)&ua;
    const __half2* pb = (const __half2*)&ub;
    float s = 0.f;
#pragma unroll
    for (int i = 0; i < 4; ++i) {
        float2 fa = __half22float2(pa[i]);
        float2 fb = __half22float2(pb[i]);
        s += fa.x * fb.x + fa.y * fb.y;
    }
    return s;
}

__global__ void __launch_bounds__(256) k_decode(
        const int* __restrict__ eli, const __half* __restrict__ enc,
        float* __restrict__ out) {
    int gid = blockIdx.x * 256 + threadIdx.x;  // EL*8 threads
    int p = gid >> 3;
    int c8 = gid & 7;  // 8 halves (16 B) per lane
    int a = eli[p];
    int b = eli[N_LABEL + p];
    uint4 ua = *(const uint4*)(enc + (size_t)a * 64 + c8 * 8);
    uint4 ub = *(const uint4*)(enc + (size_t)b * 64 + c8 * 8);
    float s = dot8h(ua, ub);
    s += __shfl_xor(s, 1, 8);
    s += __shfl_xor(s, 2, 8);
    s += __shfl_xor(s, 4, 8);
    if (c8 == 0) out[p] = s;
}

// ---------------- host ----------------

extern "C" void kernel_launch(void* const* d_in, const int* in_sizes, int n_in,
                              void* d_out, int out_size, void* d_ws, size_t ws_size,
                              hipStream_t stream) {
    const float* x   = (const float*)d_in[0];
    const int*   ei  = (const int*)d_in[1];
    const float* ew  = (const float*)d_in[2];
    const int*   eli = (const int*)d_in[3];
    const float* W[6] = {(const float*)d_in[4],  (const float*)d_in[6],
                         (const float*)d_in[8],  (const float*)d_in[10],
                         (const float*)d_in[12], (const float*)d_in[14]};
    const float* B[6] = {(const float*)d_in[5],  (const float*)d_in[7],
                         (const float*)d_in[9],  (const float*)d_in[11],
                         (const float*)d_in[13], (const float*)d_in[15]};

    char* ws = (char*)d_ws;
    float*  dinv    = (float*)ws;   ws += N_NODES * 4;
    int*    cnt     = (int*)ws;     ws += N_NODES * 4;
    int*    offs    = (int*)ws;     ws += (N_NODES + 16) * 4;
    int*    cursor  = (int*)ws;     ws += N_NODES * 4;
    int*    blksum  = (int*)ws;     ws += 256 * 4;
    int2*   csr_se  = (int2*)ws;    ws += (size_t)N_EDGES * 8;
    __half* xh      = (__half*)ws;  ws += (size_t)N_NODES * DIM_IN * 2;
    __half* hA      = (__half*)ws;  ws += (size_t)N_NODES * 64 * 2;
    __half* hB      = (__half*)ws;

    const int BS = 256;
    const int gLayer = N_NODES / 4;  // one 64-lane wave per node, 4 per block

    // CSR build + norm
    k_init <<<N_NODES / BS, BS, 0, stream>>>(dinv, cnt);
    k_cnt  <<<N_EDGES / BS, BS, 0, stream>>>(ei, ew, cnt, dinv);
    k_scan1<<<64, BS, 0, stream>>>(cnt, blksum);
    k_scan2<<<1, 64, 0, stream>>>(blksum);
    k_scan3<<<64, BS, 0, stream>>>(cnt, blksum, offs, cursor);
    k_dinv <<<N_NODES / BS, BS, 0, stream>>>(dinv);
    k_fill <<<N_EDGES / BS, BS, 0, stream>>>(ei, ew, dinv, cursor, csr_se);

    // cast x to fp16
    k_cast_x<<<N_NODES * DIM_IN / BS, BS, 0, stream>>>(x, xh);

    // fused layers (fp16 tables, fp32 math)
    k_layer<DIM_IN, true ><<<gLayer, BS, 0, stream>>>(offs, csr_se, xh, dinv, W[0], B[0], hA);
    k_layer<DIM_H,  true ><<<gLayer, BS, 0, stream>>>(offs, csr_se, hA, dinv, W[1], B[1], hB);
    k_layer<DIM_H,  true ><<<gLayer, BS, 0, stream>>>(offs, csr_se, hB, dinv, W[2], B[2], hA);
    k_layer<DIM_H,  true ><<<gLayer, BS, 0, stream>>>(offs, csr_se, hA, dinv, W[3], B[3], hB);
    k_layer<DIM_H,  true ><<<gLayer, BS, 0, stream>>>(offs, csr_se, hB, dinv, W[4], B[4], hA);
    k_layer<DIM_H, false><<<gLayer, BS, 0, stream>>>(offs, csr_se, hA, dinv, W[5], B[5], hB);

    // decode (8 lanes per pair)
    k_decode<<<N_LABEL * 8 / BS, BS, 0, stream>>>(eli, hB, (float*)d_out);
}

// Round 9
// 732.583 us; speedup vs baseline: 1.9301x; 1.0088x over previous
//
#include <hip/hip_runtime.h>
#include <hip/hip_fp16.h>

#define N_NODES 65536
#define N_EDGES 1048576
#define N_LABEL 2097152
#define DIM_IN 32
#define DIM_H 64

// ---------------- CSR build + norm precompute ----------------

__global__ void k_init(float* __restrict__ deg, int* __restrict__ cnt) {
    int v = blockIdx.x * blockDim.x + threadIdx.x;
    deg[v] = 1.0f;  // self-loop weight
    cnt[v] = 0;
}

__global__ void k_cnt(const int* __restrict__ ei, const float* __restrict__ w,
                      int* __restrict__ cnt, float* __restrict__ deg) {
    int e = blockIdx.x * blockDim.x + threadIdx.x;
    int d = ei[N_EDGES + e];
    atomicAdd(&cnt[d], 1);
    atomicAdd(&deg[d], w[e]);
}

// hierarchical exclusive scan over cnt[N] (64 blocks x 1024)
__global__ void k_scan1(const int* __restrict__ cnt, int* __restrict__ blksum) {
    int tid = threadIdx.x;
    const int4* p = (const int4*)(cnt + blockIdx.x * 1024);
    int4 v = p[tid];
    int s = v.x + v.y + v.z + v.w;
    for (int d = 1; d < 64; d <<= 1) s += __shfl_xor(s, d);
    __shared__ int wsum[4];
    if ((tid & 63) == 0) wsum[tid >> 6] = s;
    __syncthreads();
    if (tid == 0) blksum[blockIdx.x] = wsum[0] + wsum[1] + wsum[2] + wsum[3];
}

__global__ void k_scan2(int* __restrict__ blksum) {
    if (threadIdx.x == 0) {
        int run = 0;
        for (int i = 0; i < 64; ++i) { int t = blksum[i]; blksum[i] = run; run += t; }
    }
}

__global__ void k_scan3(const int* __restrict__ cnt, const int* __restrict__ blksum,
                        int* __restrict__ offs, int* __restrict__ cursor) {
    int tid = threadIdx.x, bid = blockIdx.x;
    const int4* p = (const int4*)(cnt + bid * 1024);
    int4 v = p[tid];
    int s = v.x + v.y + v.z + v.w;
    int lane = tid & 63, wid = tid >> 6;
    int sc = s;
    for (int d = 1; d < 64; d <<= 1) {
        int t = __shfl_up(sc, d);
        if (lane >= d) sc += t;
    }
    __shared__ int wsum[4];
    if (lane == 63) wsum[wid] = sc;
    __syncthreads();
    int base = blksum[bid];
    for (int w2 = 0; w2 < wid; ++w2) base += wsum[w2];
    int ex = base + sc - s;  // exclusive prefix of this thread's 4 entries
    int idx = bid * 1024 + tid * 4;
    int o0 = ex, o1 = o0 + v.x, o2 = o1 + v.y, o3 = o2 + v.z;
    offs[idx] = o0; offs[idx + 1] = o1; offs[idx + 2] = o2; offs[idx + 3] = o3;
    cursor[idx] = o0; cursor[idx + 1] = o1; cursor[idx + 2] = o2; cursor[idx + 3] = o3;
    if (bid == 63 && tid == 255) offs[N_NODES] = o3 + v.w;  // == N_EDGES
}

__global__ void k_dinv(float* __restrict__ deg) {
    int v = blockIdx.x * blockDim.x + threadIdx.x;
    deg[v] = rsqrtf(deg[v]);
}

// packed CSR entry: {src, norm-as-bits} -> int pairs [2e]=src, [2e+1]=nrm
__global__ void k_fill(const int* __restrict__ ei, const float* __restrict__ w,
                       const float* __restrict__ dinv, int* __restrict__ cursor,
                       int2* __restrict__ csr_se) {
    int e = blockIdx.x * blockDim.x + threadIdx.x;
    int s = ei[e];
    int d = ei[N_EDGES + e];
    int pos = atomicAdd(&cursor[d], 1);
    float nm = dinv[s] * w[e] * dinv[d];
    csr_se[pos] = make_int2(s, __float_as_int(nm));
}

// ---------------- cast x to fp16 ----------------

__global__ void k_cast_x(const float* __restrict__ x, __half* __restrict__ xh) {
    int gid = blockIdx.x * 256 + threadIdx.x;  // N*32 threads
    xh[gid] = __float2half(x[gid]);
}

// ---------------- fused layer: out[v] = half( relu( (Ah)[v] @ W + b ) ) ----------------
// One 64-lane wave per node. Lane split: parity p = lane/M picks an edge within the
// packed group, m = lane%M picks a half2 of the row -> NP edges gathered per load
// instruction (2x128 B for K=64). 16-edge windows: metadata for the whole window is
// ONE coalesced 128 B load (32 lanes x int) distributed by shfl -> no serial
// broadcast-load round, and 16 in-flight edges cost only 16/NP dest VGPRs.

template <int K, bool RELU>
__global__ void __launch_bounds__(256) k_layer(
        const int* __restrict__ offs, const int* __restrict__ csr_i,
        const __half* __restrict__ h, const float* __restrict__ dinv,
        const float* __restrict__ W, const float* __restrict__ b,
        __half* __restrict__ out) {
    __shared__ float Wl[K * 64];
    int tid = threadIdx.x;
    for (int i = tid; i < K * 64; i += 256) Wl[i] = W[i];
    __syncthreads();

    constexpr int M  = K / 2;        // half2 lanes per edge row (32 or 16)
    constexpr int NP = 64 / M;       // edges per load instruction (2 or 4)
    constexpr int U  = 16 / NP;      // unroll steps per 16-edge window (8 or 4)

    int v = blockIdx.x * 4 + (tid >> 6);
    int lane = tid & 63;
    int p = lane / M;
    int m = lane % M;

    float ax = 0.f, ay = 0.f;
    if (p == 0) {  // self-loop term (parity 0 only; others start at 0)
        float dv = dinv[v];
        float sl = dv * dv;
        half2 hv = *(const half2*)(h + (size_t)v * K + m * 2);
        float2 f = __half22float2(hv);
        ax = sl * f.x;
        ay = sl * f.y;
    }

    int j0 = __builtin_amdgcn_readfirstlane(offs[v]);
    int j1 = __builtin_amdgcn_readfirstlane(offs[v + 1]);

    for (int j = j0; j < j1; j += 16) {
        // one coalesced 128 B metadata load for 16 edges (clamped in-range)
        int idx = 2 * j + (lane & 31);
        int mdv = csr_i[idx < 2 * j1 ? idx : 2 * j0];

        half2 r[U];
        float nm[U];
#pragma unroll
        for (int u = 0; u < U; ++u) {
            int w = NP * u + p;                       // edge slot in window
            int src = __shfl(mdv, 2 * w);
            float nv = __int_as_float(__shfl(mdv, 2 * w + 1));
            nm[u] = (j + w < j1) ? nv : 0.f;
            r[u] = *(const half2*)(h + (size_t)src * K + m * 2);
        }
#pragma unroll
        for (int u = 0; u < U; ++u) {
            float2 f = __half22float2(r[u]);
            ax += nm[u] * f.x;
            ay += nm[u] * f.y;
        }
    }

    // combine parity partial sums
    if (NP == 4) { ax += __shfl_xor(ax, 16); ay += __shfl_xor(ay, 16); }
    ax += __shfl_xor(ax, 32);
    ay += __shfl_xor(ay, 32);

    // transform: o[lane] = sum_k agg[k] * W[k][lane] + b[lane]
    float o = b[lane];
#pragma unroll
    for (int mm = 0; mm < M; ++mm) {
        o += __shfl(ax, mm) * Wl[(2 * mm) * 64 + lane];
        o += __shfl(ay, mm) * Wl[(2 * mm + 1) * 64 + lane];
    }
    if (RELU) o = fmaxf(o, 0.f);
    out[(size_t)v * 64 + lane] = __float2half(o);
}

// ---------------- decode: out[p] = dot(enc[a], enc[b]); 8 lanes/pair, fp16 rows ----------------

__device__ __forceinline__ float dot8h(uint4 ua, uint4 ub) {
    const __half2* pa = (const __half2*)&ua;
    const __half2* pb = (const __half2*)&ub;
    float s = 0.f;
#pragma unroll
    for (int i = 0; i < 4; ++i) {
        float2 fa = __half22float2(pa[i]);
        float2 fb = __half22float2(pb[i]);
        s += fa.x * fb.x + fa.y * fb.y;
    }
    return s;
}

__global__ void __launch_bounds__(256) k_decode(
        const int* __restrict__ eli, const __half* __restrict__ enc,
        float* __restrict__ out) {
    int gid = blockIdx.x * 256 + threadIdx.x;  // EL*8 threads
    int p = gid >> 3;
    int c8 = gid & 7;  // 8 halves (16 B) per lane
    int a = eli[p];
    int b = eli[N_LABEL + p];
    uint4 ua = *(const uint4*)(enc + (size_t)a * 64 + c8 * 8);
    uint4 ub = *(const uint4*)(enc + (size_t)b * 64 + c8 * 8);
    float s = dot8h(ua, ub);
    s += __shfl_xor(s, 1, 8);
    s += __shfl_xor(s, 2, 8);
    s += __shfl_xor(s, 4, 8);
    if (c8 == 0) out[p] = s;
}

// ---------------- host ----------------

extern "C" void kernel_launch(void* const* d_in, const int* in_sizes, int n_in,
                              void* d_out, int out_size, void* d_ws, size_t ws_size,
                              hipStream_t stream) {
    const float* x   = (const float*)d_in[0];
    const int*   ei  = (const int*)d_in[1];
    const float* ew  = (const float*)d_in[2];
    const int*   eli = (const int*)d_in[3];
    const float* W[6] = {(const float*)d_in[4],  (const float*)d_in[6],
                         (const float*)d_in[8],  (const float*)d_in[10],
                         (const float*)d_in[12], (const float*)d_in[14]};
    const float* B[6] = {(const float*)d_in[5],  (const float*)d_in[7],
                         (const float*)d_in[9],  (const float*)d_in[11],
                         (const float*)d_in[13], (const float*)d_in[15]};

    char* ws = (char*)d_ws;
    float*  dinv    = (float*)ws;   ws += N_NODES * 4;
    int*    cnt     = (int*)ws;     ws += N_NODES * 4;
    int*    offs    = (int*)ws;     ws += (N_NODES + 16) * 4;
    int*    cursor  = (int*)ws;     ws += N_NODES * 4;
    int*    blksum  = (int*)ws;     ws += 256 * 4;
    int2*   csr_se  = (int2*)ws;    ws += (size_t)N_EDGES * 8;
    __half* xh      = (__half*)ws;  ws += (size_t)N_NODES * DIM_IN * 2;
    __half* hA      = (__half*)ws;  ws += (size_t)N_NODES * 64 * 2;
    __half* hB      = (__half*)ws;

    const int BS = 256;
    const int gLayer = N_NODES / 4;  // one 64-lane wave per node, 4 per block

    // CSR build + norm
    k_init <<<N_NODES / BS, BS, 0, stream>>>(dinv, cnt);
    k_cnt  <<<N_EDGES / BS, BS, 0, stream>>>(ei, ew, cnt, dinv);
    k_scan1<<<64, BS, 0, stream>>>(cnt, blksum);
    k_scan2<<<1, 64, 0, stream>>>(blksum);
    k_scan3<<<64, BS, 0, stream>>>(cnt, blksum, offs, cursor);
    k_dinv <<<N_NODES / BS, BS, 0, stream>>>(dinv);
    k_fill <<<N_EDGES / BS, BS, 0, stream>>>(ei, ew, dinv, cursor, csr_se);

    // cast x to fp16
    k_cast_x<<<N_NODES * DIM_IN / BS, BS, 0, stream>>>(x, xh);

    const int* csr_i = (const int*)csr_se;

    // fused layers (fp16 tables, fp32 math)
    k_layer<DIM_IN, true ><<<gLayer, BS, 0, stream>>>(offs, csr_i, xh, dinv, W[0], B[0], hA);
    k_layer<DIM_H,  true ><<<gLayer, BS, 0, stream>>>(offs, csr_i, hA, dinv, W[1], B[1], hB);
    k_layer<DIM_H,  true ><<<gLayer, BS, 0, stream>>>(offs, csr_i, hB, dinv, W[2], B[2], hA);
    k_layer<DIM_H,  true ><<<gLayer, BS, 0, stream>>>(offs, csr_i, hA, dinv, W[3], B[3], hB);
    k_layer<DIM_H,  true ><<<gLayer, BS, 0, stream>>>(offs, csr_i, hB, dinv, W[4], B[4], hA);
    k_layer<DIM_H, false><<<gLayer, BS, 0, stream>>>(offs, csr_i, hA, dinv, W[5], B[5], hB);

    // decode (8 lanes per pair)
    k_decode<<<N_LABEL * 8 / BS, BS, 0, stream>>>(eli, hB, (float*)d_out);
}

// Round 10
// 731.763 us; speedup vs baseline: 1.9323x; 1.0011x over previous
//
#include <hip/hip_runtime.h>
#include <hip/hip_fp16.h>

#define N_NODES 65536
#define N_EDGES 1048576
#define N_LABEL 2097152
#define DIM_IN 32
#define DIM_H 64

// ---------------- CSR build + norm precompute ----------------

__global__ void k_init(float* __restrict__ deg, int* __restrict__ cnt) {
    int v = blockIdx.x * blockDim.x + threadIdx.x;
    deg[v] = 1.0f;  // self-loop weight
    cnt[v] = 0;
}

__global__ void k_cnt(const int* __restrict__ ei, const float* __restrict__ w,
                      int* __restrict__ cnt, float* __restrict__ deg) {
    int e = blockIdx.x * blockDim.x + threadIdx.x;
    int d = ei[N_EDGES + e];
    atomicAdd(&cnt[d], 1);
    atomicAdd(&deg[d], w[e]);
}

// hierarchical exclusive scan over cnt[N] (64 blocks x 1024)
__global__ void k_scan1(const int* __restrict__ cnt, int* __restrict__ blksum) {
    int tid = threadIdx.x;
    const int4* p = (const int4*)(cnt + blockIdx.x * 1024);
    int4 v = p[tid];
    int s = v.x + v.y + v.z + v.w;
    for (int d = 1; d < 64; d <<= 1) s += __shfl_xor(s, d);
    __shared__ int wsum[4];
    if ((tid & 63) == 0) wsum[tid >> 6] = s;
    __syncthreads();
    if (tid == 0) blksum[blockIdx.x] = wsum[0] + wsum[1] + wsum[2] + wsum[3];
}

__global__ void k_scan2(int* __restrict__ blksum) {
    if (threadIdx.x == 0) {
        int run = 0;
        for (int i = 0; i < 64; ++i) { int t = blksum[i]; blksum[i] = run; run += t; }
    }
}

__global__ void k_scan3(const int* __restrict__ cnt, const int* __restrict__ blksum,
                        int* __restrict__ offs, int* __restrict__ cursor) {
    int tid = threadIdx.x, bid = blockIdx.x;
    const int4* p = (const int4*)(cnt + bid * 1024);
    int4 v = p[tid];
    int s = v.x + v.y + v.z + v.w;
    int lane = tid & 63, wid = tid >> 6;
    int sc = s;
    for (int d = 1; d < 64; d <<= 1) {
        int t = __shfl_up(sc, d);
        if (lane >= d) sc += t;
    }
    __shared__ int wsum[4];
    if (lane == 63) wsum[wid] = sc;
    __syncthreads();
    int base = blksum[bid];
    for (int w2 = 0; w2 < wid; ++w2) base += wsum[w2];
    int ex = base + sc - s;  // exclusive prefix of this thread's 4 entries
    int idx = bid * 1024 + tid * 4;
    int o0 = ex, o1 = o0 + v.x, o2 = o1 + v.y, o3 = o2 + v.z;
    offs[idx] = o0; offs[idx + 1] = o1; offs[idx + 2] = o2; offs[idx + 3] = o3;
    cursor[idx] = o0; cursor[idx + 1] = o1; cursor[idx + 2] = o2; cursor[idx + 3] = o3;
    if (bid == 63 && tid == 255) offs[N_NODES] = o3 + v.w;  // == N_EDGES
}

__global__ void k_dinv(float* __restrict__ deg) {
    int v = blockIdx.x * blockDim.x + threadIdx.x;
    deg[v] = rsqrtf(deg[v]);
}

// packed CSR entry: {src, norm-as-bits} -> int pairs [2e]=src, [2e+1]=nrm
__global__ void k_fill(const int* __restrict__ ei, const float* __restrict__ w,
                       const float* __restrict__ dinv, int* __restrict__ cursor,
                       int2* __restrict__ csr_se) {
    int e = blockIdx.x * blockDim.x + threadIdx.x;
    int s = ei[e];
    int d = ei[N_EDGES + e];
    int pos = atomicAdd(&cursor[d], 1);
    float nm = dinv[s] * w[e] * dinv[d];
    csr_se[pos] = make_int2(s, __float_as_int(nm));
}

// ---------------- cast x to fp16 ----------------

__global__ void k_cast_x(const float* __restrict__ x, __half* __restrict__ xh) {
    int gid = blockIdx.x * 256 + threadIdx.x;  // N*32 threads
    xh[gid] = __float2half(x[gid]);
}

// ---------------- fused layer: out[v] = half( relu( (Ah)[v] @ W + b ) ) ----------------
// One 64-lane wave per node. Lane split: parity p = lane/M picks an edge within the
// packed group, m = lane%M picks a half2 of the row -> NP edges gathered per load
// instruction (2x128 B for K=64). 16-edge windows: metadata for the whole window is
// ONE coalesced 128 B load (32 lanes x int) distributed by shfl -> no serial
// broadcast-load round, and 16 in-flight edges cost only 16/NP dest VGPRs.

template <int K, bool RELU>
__global__ void __launch_bounds__(256) k_layer(
        const int* __restrict__ offs, const int* __restrict__ csr_i,
        const __half* __restrict__ h, const float* __restrict__ dinv,
        const float* __restrict__ W, const float* __restrict__ b,
        __half* __restrict__ out) {
    __shared__ float Wl[K * 64];
    int tid = threadIdx.x;
    for (int i = tid; i < K * 64; i += 256) Wl[i] = W[i];
    __syncthreads();

    constexpr int M  = K / 2;        // half2 lanes per edge row (32 or 16)
    constexpr int NP = 64 / M;       // edges per load instruction (2 or 4)
    constexpr int U  = 16 / NP;      // unroll steps per 16-edge window (8 or 4)

    int v = blockIdx.x * 4 + (tid >> 6);
    int lane = tid & 63;
    int p = lane / M;
    int m = lane % M;

    float ax = 0.f, ay = 0.f;
    if (p == 0) {  // self-loop term (parity 0 only; others start at 0)
        float dv = dinv[v];
        float sl = dv * dv;
        half2 hv = *(const half2*)(h + (size_t)v * K + m * 2);
        float2 f = __half22float2(hv);
        ax = sl * f.x;
        ay = sl * f.y;
    }

    int j0 = __builtin_amdgcn_readfirstlane(offs[v]);
    int j1 = __builtin_amdgcn_readfirstlane(offs[v + 1]);

    for (int j = j0; j < j1; j += 16) {
        // one coalesced 128 B metadata load for 16 edges (clamped in-range)
        int idx = 2 * j + (lane & 31);
        int mdv = csr_i[idx < 2 * j1 ? idx : 2 * j0];

        half2 r[U];
        float nm[U];
#pragma unroll
        for (int u = 0; u < U; ++u) {
            int w = NP * u + p;                       // edge slot in window
            int src = __shfl(mdv, 2 * w);
            float nv = __int_as_float(__shfl(mdv, 2 * w + 1));
            nm[u] = (j + w < j1) ? nv : 0.f;
            r[u] = *(const half2*)(h + (size_t)src * K + m * 2);
        }
#pragma unroll
        for (int u = 0; u < U; ++u) {
            float2 f = __half22float2(r[u]);
            ax += nm[u] * f.x;
            ay += nm[u] * f.y;
        }
    }

    // combine parity partial sums
    if (NP == 4) { ax += __shfl_xor(ax, 16); ay += __shfl_xor(ay, 16); }
    ax += __shfl_xor(ax, 32);
    ay += __shfl_xor(ay, 32);

    // transform: o[lane] = sum_k agg[k] * W[k][lane] + b[lane]
    float o = b[lane];
#pragma unroll
    for (int mm = 0; mm < M; ++mm) {
        o += __shfl(ax, mm) * Wl[(2 * mm) * 64 + lane];
        o += __shfl(ay, mm) * Wl[(2 * mm + 1) * 64 + lane];
    }
    if (RELU) o = fmaxf(o, 0.f);
    out[(size_t)v * 64 + lane] = __float2half(o);
}

// ---------------- decode: out[p] = dot(enc[a], enc[b]); 8 lanes/pair, fp16 rows ----------------

__device__ __forceinline__ float dot8h(uint4 ua, uint4 ub) {
    const __half2* pa = (const __half2*)&ua;
    const __half2* pb = (const __half2*)&ub;
    float s = 0.f;
#pragma unroll
    for (int i = 0; i < 4; ++i) {
        float2 fa = __half22float2(pa[i]);
        float2 fb = __half22float2(pb[i]);
        s += fa.x * fb.x + fa.y * fb.y;
    }
    return s;
}

__global__ void __launch_bounds__(256) k_decode(
        const int* __restrict__ eli, const __half* __restrict__ enc,
        float* __restrict__ out) {
    int gid = blockIdx.x * 256 + threadIdx.x;  // EL*8 threads
    int p = gid >> 3;
    int c8 = gid & 7;  // 8 halves (16 B) per lane
    int a = eli[p];
    int b = eli[N_LABEL + p];
    uint4 ua = *(const uint4*)(enc + (size_t)a * 64 + c8 * 8);
    uint4 ub = *(const uint4*)(enc + (size_t)b * 64 + c8 * 8);
    float s = dot8h(ua, ub);
    s += __shfl_xor(s, 1, 8);
    s += __shfl_xor(s, 2, 8);
    s += __shfl_xor(s, 4, 8);
    if (c8 == 0) out[p] = s;
}

// ---------------- host ----------------

extern "C" void kernel_launch(void* const* d_in, const int* in_sizes, int n_in,
                              void* d_out, int out_size, void* d_ws, size_t ws_size,
                              hipStream_t stream) {
    const float* x   = (const float*)d_in[0];
    const int*   ei  = (const int*)d_in[1];
    const float* ew  = (const float*)d_in[2];
    const int*   eli = (const int*)d_in[3];
    const float* W[6] = {(const float*)d_in[4],  (const float*)d_in[6],
                         (const float*)d_in[8],  (const float*)d_in[10],
                         (const float*)d_in[12], (const float*)d_in[14]};
    const float* B[6] = {(const float*)d_in[5],  (const float*)d_in[7],
                         (const float*)d_in[9],  (const float*)d_in[11],
                         (const float*)d_in[13], (const float*)d_in[15]};

    char* ws = (char*)d_ws;
    float*  dinv    = (float*)ws;   ws += N_NODES * 4;
    int*    cnt     = (int*)ws;     ws += N_NODES * 4;
    int*    offs    = (int*)ws;     ws += (N_NODES + 16) * 4;
    int*    cursor  = (int*)ws;     ws += N_NODES * 4;
    int*    blksum  = (int*)ws;     ws += 256 * 4;
    int2*   csr_se  = (int2*)ws;    ws += (size_t)N_EDGES * 8;
    __half* xh      = (__half*)ws;  ws += (size_t)N_NODES * DIM_IN * 2;
    __half* hA      = (__half*)ws;  ws += (size_t)N_NODES * 64 * 2;
    __half* hB      = (__half*)ws;

    const int BS = 256;
    const int gLayer = N_NODES / 4;  // one 64-lane wave per node, 4 per block

    // CSR build + norm
    k_init <<<N_NODES / BS, BS, 0, stream>>>(dinv, cnt);
    k_cnt  <<<N_EDGES / BS, BS, 0, stream>>>(ei, ew, cnt, dinv);
    k_scan1<<<64, BS, 0, stream>>>(cnt, blksum);
    k_scan2<<<1, 64, 0, stream>>>(blksum);
    k_scan3<<<64, BS, 0, stream>>>(cnt, blksum, offs, cursor);
    k_dinv <<<N_NODES / BS, BS, 0, stream>>>(dinv);
    k_fill <<<N_EDGES / BS, BS, 0, stream>>>(ei, ew, dinv, cursor, csr_se);

    // cast x to fp16
    k_cast_x<<<N_NODES * DIM_IN / BS, BS, 0, stream>>>(x, xh);

    const int* csr_i = (const int*)csr_se;

    // fused layers (fp16 tables, fp32 math)
    k_layer<DIM_IN, true ><<<gLayer, BS, 0, stream>>>(offs, csr_i, xh, dinv, W[0], B[0], hA);
    k_layer<DIM_H,  true ><<<gLayer, BS, 0, stream>>>(offs, csr_i, hA, dinv, W[1], B[1], hB);
    k_layer<DIM_H,  true ><<<gLayer, BS, 0, stream>>>(offs, csr_i, hB, dinv, W[2], B[2], hA);
    k_layer<DIM_H,  true ><<<gLayer, BS, 0, stream>>>(offs, csr_i, hA, dinv, W[3], B[3], hB);
    k_layer<DIM_H,  true ><<<gLayer, BS, 0, stream>>>(offs, csr_i, hB, dinv, W[4], B[4], hA);
    k_layer<DIM_H, false><<<gLayer, BS, 0, stream>>>(offs, csr_i, hA, dinv, W[5], B[5], hB);

    // decode (8 lanes per pair)
    k_decode<<<N_LABEL * 8 / BS, BS, 0, stream>>>(eli, hB, (float*)d_out);
}